// Round 5
// baseline (176.799 us; speedup 1.0000x reference)
//
#include <hip/hip_runtime.h>

// FastFocalLoss: scalar = -(pos_loss + neg_loss)/num_pos  (or -neg_loss if no pos)
//   neg_loss = sum log(1-o) * o^2 * (1-t)^4     over all elements
//   pos_loss = sum_{t==1} log(o) * (1-o)^2
//   num_pos  = count(t == 1.0)
// R4 post-mortem: 4 structural variants all 79-82us; memory-path-bound at
// ~5.2 TB/s aggregate (half HBM, half L3). Removable overhead left: the
// second kernel launch. R5: single fused kernel, last-block-done counter
// (integer atomic = deterministic; partials summed in fixed index order).

typedef __attribute__((ext_vector_type(4))) float f32x4;

__device__ __forceinline__ double wave_reduce_add(double v) {
    #pragma unroll
    for (int off = 32; off > 0; off >>= 1) v += __shfl_down(v, off, 64);
    return v;
}

// Block-level reduce of three doubles (256 threads = 4 waves).
__device__ __forceinline__ void block_reduce3(double& neg, double& pos, double& cnt) {
    __shared__ double s_neg[4], s_pos[4], s_cnt[4];
    neg = wave_reduce_add(neg);
    pos = wave_reduce_add(pos);
    cnt = wave_reduce_add(cnt);
    const int lane = threadIdx.x & 63;
    const int wid  = threadIdx.x >> 6;
    if (lane == 0) { s_neg[wid] = neg; s_pos[wid] = pos; s_cnt[wid] = cnt; }
    __syncthreads();
    if (wid == 0) {
        neg = (lane < 4) ? s_neg[lane] : 0.0;
        pos = (lane < 4) ? s_pos[lane] : 0.0;
        cnt = (lane < 4) ? s_cnt[lane] : 0.0;
        #pragma unroll
        for (int off = 2; off > 0; off >>= 1) {
            neg += __shfl_down(neg, off, 64);
            pos += __shfl_down(pos, off, 64);
            cnt += __shfl_down(cnt, off, 64);
        }
    }
}

__device__ __forceinline__ void accum_elem(float o, float t,
                                           float& neg, float& pos, int& cnt) {
    float g  = 1.0f - t;
    float g2 = g * g;
    neg += __logf(1.0f - o) * (o * o) * (g2 * g2);
    if (t == 1.0f) {
        float io = 1.0f - o;
        pos += __logf(o) * io * io;
        cnt += 1;
    }
}

__global__ __launch_bounds__(256)
void ffl_fused(const f32x4* __restrict__ out4, const f32x4* __restrict__ tgt4,
               int n4,
               const float* __restrict__ out_s, const float* __restrict__ tgt_s,
               int tail_start, int n,
               double* __restrict__ ws, unsigned int* __restrict__ counter,
               int nblocks, float* __restrict__ result) {
    float negf = 0.0f, posf = 0.0f;
    int cnt = 0;
    const int idx    = (int)blockIdx.x * 256 + (int)threadIdx.x;
    const int stride = (int)gridDim.x * 256;

    #pragma unroll 4
    for (int i = idx; i < n4; i += stride) {
        f32x4 o = out4[i];
        f32x4 t = tgt4[i];
        accum_elem(o.x, t.x, negf, posf, cnt);
        accum_elem(o.y, t.y, negf, posf, cnt);
        accum_elem(o.z, t.z, negf, posf, cnt);
        accum_elem(o.w, t.w, negf, posf, cnt);
    }
    // scalar tail (n not divisible by 4)
    for (int j = tail_start + idx; j < n; j += stride) {
        accum_elem(out_s[j], tgt_s[j], negf, posf, cnt);
    }

    double neg = (double)negf, pos = (double)posf, c = (double)cnt;
    block_reduce3(neg, pos, c);

    __shared__ int s_is_last;
    if (threadIdx.x == 0) {
        ws[3 * blockIdx.x + 0] = neg;
        ws[3 * blockIdx.x + 1] = pos;
        ws[3 * blockIdx.x + 2] = c;
        __threadfence();                       // make partials visible device-wide
        unsigned int old = atomicAdd(counter, 1u);
        s_is_last = (old == (unsigned int)(nblocks - 1));
    }
    __syncthreads();                           // broadcast + protect s_* reuse

    if (s_is_last) {
        __threadfence();                       // acquire all blocks' partials
        double fneg = 0.0, fpos = 0.0, fcnt = 0.0;
        for (int i = (int)threadIdx.x; i < nblocks; i += 256) {
            fneg += ws[3 * i + 0];
            fpos += ws[3 * i + 1];
            fcnt += ws[3 * i + 2];
        }
        block_reduce3(fneg, fpos, fcnt);
        if (threadIdx.x == 0) {
            double r = (fcnt == 0.0) ? (-fneg) : (-(fpos + fneg) / fcnt);
            result[0] = (float)r;
        }
    }
}

extern "C" void kernel_launch(void* const* d_in, const int* in_sizes, int n_in,
                              void* d_out, int out_size, void* d_ws, size_t ws_size,
                              hipStream_t stream) {
    const float* outp = (const float*)d_in[0];
    const float* tgtp = (const float*)d_in[1];
    const int n  = in_sizes[0];
    const int n4 = n >> 2;            // float4 count
    const int tail_start = n4 << 2;

    double* ws = (double*)d_ws;
    int blocks = 2048;                 // 8 blocks/CU at 256 thr = full occupancy
    // layout: [0, 3*blocks) doubles = partials; counter at byte 3*blocks*8
    const int max_blocks = (int)((ws_size - sizeof(unsigned int)) / (3 * sizeof(double)));
    if (blocks > max_blocks) blocks = max_blocks;
    if (blocks < 1) blocks = 1;
    unsigned int* counter = (unsigned int*)((char*)d_ws + (size_t)blocks * 3 * sizeof(double));

    // reset the done-counter each call (captured in the graph; deterministic)
    hipMemsetAsync(counter, 0, sizeof(unsigned int), stream);

    ffl_fused<<<blocks, 256, 0, stream>>>(
        (const f32x4*)outp, (const f32x4*)tgtp, n4,
        outp, tgtp, tail_start, n,
        ws, counter, blocks, (float*)d_out);
}

// Round 6
// 93.345 us; speedup vs baseline: 1.8940x; 1.8940x over previous
//
#include <hip/hip_runtime.h>

// FastFocalLoss: scalar = -(pos_loss + neg_loss)/num_pos  (or -neg_loss if no pos)
//   neg_loss = sum log(1-o) * o^2 * (1-t)^4     over all elements
//   pos_loss = sum_{t==1} log(o) * (1-o)^2
//   num_pos  = count(t == 1.0)
// R5 post-mortem: per-block __threadfence() = agent-scope release = L2
// writeback-INVALIDATE per block on multi-XCD CDNA4 -> main loop halved in
// throughput (FETCH flat, VALUBusy halved). R6: fence-free fusion — f64
// atomicAdd partials into 64 slots (atomics are fine-grained at the coherence
// point, no cache invalidation), s_waitcnt vmcnt(0) before the done-counter
// bump (guarantees adds are globally performed), last block reads slots back
// via atomic RMW-reads. No __threadfence anywhere.

typedef __attribute__((ext_vector_type(4))) float f32x4;

#define NSLOT 64   // contention spreading: 2048 blocks -> 32 adds/slot/term

__device__ __forceinline__ double wave_reduce_add(double v) {
    #pragma unroll
    for (int off = 32; off > 0; off >>= 1) v += __shfl_down(v, off, 64);
    return v;
}

// Block-level reduce of three doubles (256 threads = 4 waves).
__device__ __forceinline__ void block_reduce3(double& neg, double& pos, double& cnt) {
    __shared__ double s_neg[4], s_pos[4], s_cnt[4];
    neg = wave_reduce_add(neg);
    pos = wave_reduce_add(pos);
    cnt = wave_reduce_add(cnt);
    const int lane = threadIdx.x & 63;
    const int wid  = threadIdx.x >> 6;
    if (lane == 0) { s_neg[wid] = neg; s_pos[wid] = pos; s_cnt[wid] = cnt; }
    __syncthreads();
    if (wid == 0) {
        neg = (lane < 4) ? s_neg[lane] : 0.0;
        pos = (lane < 4) ? s_pos[lane] : 0.0;
        cnt = (lane < 4) ? s_cnt[lane] : 0.0;
        #pragma unroll
        for (int off = 2; off > 0; off >>= 1) {
            neg += __shfl_down(neg, off, 64);
            pos += __shfl_down(pos, off, 64);
            cnt += __shfl_down(cnt, off, 64);
        }
    }
}

__device__ __forceinline__ void accum_elem(float o, float t,
                                           float& neg, float& pos, int& cnt) {
    float g  = 1.0f - t;
    float g2 = g * g;
    neg += __logf(1.0f - o) * (o * o) * (g2 * g2);
    if (t == 1.0f) {
        float io = 1.0f - o;
        pos += __logf(o) * io * io;
        cnt += 1;
    }
}

__global__ __launch_bounds__(256)
void ffl_fused(const f32x4* __restrict__ out4, const f32x4* __restrict__ tgt4,
               int n4,
               const float* __restrict__ out_s, const float* __restrict__ tgt_s,
               int tail_start, int n,
               double* __restrict__ slots, unsigned int* __restrict__ counter,
               int nblocks, float* __restrict__ result) {
    float negf = 0.0f, posf = 0.0f;
    int cnt = 0;
    const int idx    = (int)blockIdx.x * 256 + (int)threadIdx.x;
    const int stride = (int)gridDim.x * 256;

    #pragma unroll 4
    for (int i = idx; i < n4; i += stride) {
        f32x4 o = out4[i];
        f32x4 t = tgt4[i];
        accum_elem(o.x, t.x, negf, posf, cnt);
        accum_elem(o.y, t.y, negf, posf, cnt);
        accum_elem(o.z, t.z, negf, posf, cnt);
        accum_elem(o.w, t.w, negf, posf, cnt);
    }
    // scalar tail (n not divisible by 4)
    for (int j = tail_start + idx; j < n; j += stride) {
        accum_elem(out_s[j], tgt_s[j], negf, posf, cnt);
    }

    double neg = (double)negf, pos = (double)posf, c = (double)cnt;
    block_reduce3(neg, pos, c);

    __shared__ int s_is_last;
    if (threadIdx.x == 0) {
        const int slot = (int)blockIdx.x & (NSLOT - 1);
        atomicAdd(&slots[3 * slot + 0], neg);
        atomicAdd(&slots[3 * slot + 1], pos);
        atomicAdd(&slots[3 * slot + 2], c);
        // Drain the atomics (wave-local wait, NOT a cache-invalidating fence):
        // once vmcnt==0 the RMWs are globally performed at the coherence point.
        asm volatile("s_waitcnt vmcnt(0)" ::: "memory");
        unsigned int old = atomicAdd(counter, 1u);
        s_is_last = (old == (unsigned int)(nblocks - 1));
    }
    __syncthreads();

    if (s_is_last) {
        const int lane = (int)threadIdx.x & 63;
        const int wid  = (int)threadIdx.x >> 6;
        if (wid == 0) {
            double fneg = 0.0, fpos = 0.0, fcnt = 0.0;
            if (lane < NSLOT) {
                // atomic RMW-reads: coherent view of all slots
                fneg = atomicAdd(&slots[3 * lane + 0], 0.0);
                fpos = atomicAdd(&slots[3 * lane + 1], 0.0);
                fcnt = atomicAdd(&slots[3 * lane + 2], 0.0);
            }
            fneg = wave_reduce_add(fneg);
            fpos = wave_reduce_add(fpos);
            fcnt = wave_reduce_add(fcnt);
            if (lane == 0) {
                double r = (fcnt == 0.0) ? (-fneg) : (-(fpos + fneg) / fcnt);
                result[0] = (float)r;
            }
        }
    }
}

extern "C" void kernel_launch(void* const* d_in, const int* in_sizes, int n_in,
                              void* d_out, int out_size, void* d_ws, size_t ws_size,
                              hipStream_t stream) {
    const float* outp = (const float*)d_in[0];
    const float* tgtp = (const float*)d_in[1];
    const int n  = in_sizes[0];
    const int n4 = n >> 2;            // float4 count
    const int tail_start = n4 << 2;

    // ws layout: [0, NSLOT*3) doubles = slot accumulators; u32 counter after.
    double* slots = (double*)d_ws;
    unsigned int* counter = (unsigned int*)((char*)d_ws + NSLOT * 3 * sizeof(double));

    int blocks = 2048;                 // 8 blocks/CU at 256 thr = full occupancy

    // zero slots + counter every call (graph-captured, deterministic)
    hipMemsetAsync(d_ws, 0, NSLOT * 3 * sizeof(double) + sizeof(unsigned int), stream);

    ffl_fused<<<blocks, 256, 0, stream>>>(
        (const f32x4*)outp, (const f32x4*)tgtp, n4,
        outp, tgtp, tail_start, n,
        slots, counter, blocks, (float*)d_out);
}

// Round 7
// 72.754 us; speedup vs baseline: 2.4301x; 1.2830x over previous
//
#include <hip/hip_runtime.h>

// FastFocalLoss: scalar = -(pos_loss + neg_loss)/num_pos  (or -neg_loss if no pos)
//   neg_loss = sum log(1-o) * o^2 * (1-t)^4     over all elements
//   pos_loss = sum_{t==1} log(o) * (1-o)^2
//   num_pos  = count(t == 1.0)
// R6 post-mortem: fused tail costs more than the 2nd launch (93 vs 79us);
// two-kernel structure restored. R7 probe: nontemporal loads on both input
// streams (read-exactly-once data; stop thrashing L3 across replays, stream
// all 402MB from HBM). Discriminates "fabric read ceiling ~5.3 TB/s" vs
// "mixed L3/HBM interleave penalty".

typedef __attribute__((ext_vector_type(4))) float f32x4;

__device__ __forceinline__ double wave_reduce_add(double v) {
    #pragma unroll
    for (int off = 32; off > 0; off >>= 1) v += __shfl_down(v, off, 64);
    return v;
}

// Block-level reduce of three doubles (256 threads = 4 waves).
__device__ __forceinline__ void block_reduce3(double& neg, double& pos, double& cnt) {
    __shared__ double s_neg[4], s_pos[4], s_cnt[4];
    neg = wave_reduce_add(neg);
    pos = wave_reduce_add(pos);
    cnt = wave_reduce_add(cnt);
    const int lane = threadIdx.x & 63;
    const int wid  = threadIdx.x >> 6;
    if (lane == 0) { s_neg[wid] = neg; s_pos[wid] = pos; s_cnt[wid] = cnt; }
    __syncthreads();
    if (wid == 0) {
        neg = (lane < 4) ? s_neg[lane] : 0.0;
        pos = (lane < 4) ? s_pos[lane] : 0.0;
        cnt = (lane < 4) ? s_cnt[lane] : 0.0;
        #pragma unroll
        for (int off = 2; off > 0; off >>= 1) {
            neg += __shfl_down(neg, off, 64);
            pos += __shfl_down(pos, off, 64);
            cnt += __shfl_down(cnt, off, 64);
        }
    }
}

__device__ __forceinline__ void accum_elem(float o, float t,
                                           float& neg, float& pos, int& cnt) {
    float g  = 1.0f - t;
    float g2 = g * g;
    neg += __logf(1.0f - o) * (o * o) * (g2 * g2);
    if (t == 1.0f) {
        float io = 1.0f - o;
        pos += __logf(o) * io * io;
        cnt += 1;
    }
}

__global__ __launch_bounds__(256)
void ffl_partial(const f32x4* __restrict__ out4, const f32x4* __restrict__ tgt4,
                 int n4,
                 const float* __restrict__ out_s, const float* __restrict__ tgt_s,
                 int tail_start, int n,
                 double* __restrict__ ws) {
    float negf = 0.0f, posf = 0.0f;
    int cnt = 0;
    const int idx    = (int)blockIdx.x * 256 + (int)threadIdx.x;
    const int stride = (int)gridDim.x * 256;

    #pragma unroll 4
    for (int i = idx; i < n4; i += stride) {
        f32x4 o = __builtin_nontemporal_load(&out4[i]);
        f32x4 t = __builtin_nontemporal_load(&tgt4[i]);
        accum_elem(o.x, t.x, negf, posf, cnt);
        accum_elem(o.y, t.y, negf, posf, cnt);
        accum_elem(o.z, t.z, negf, posf, cnt);
        accum_elem(o.w, t.w, negf, posf, cnt);
    }
    // scalar tail (n not divisible by 4)
    for (int j = tail_start + idx; j < n; j += stride) {
        float o = __builtin_nontemporal_load(&out_s[j]);
        float t = __builtin_nontemporal_load(&tgt_s[j]);
        accum_elem(o, t, negf, posf, cnt);
    }

    double neg = (double)negf, pos = (double)posf, c = (double)cnt;
    block_reduce3(neg, pos, c);
    if (threadIdx.x == 0) {
        ws[3 * blockIdx.x + 0] = neg;
        ws[3 * blockIdx.x + 1] = pos;
        ws[3 * blockIdx.x + 2] = c;
    }
}

__global__ __launch_bounds__(256)
void ffl_final(const double* __restrict__ ws, int nparts, float* __restrict__ out) {
    double neg = 0.0, pos = 0.0, cnt = 0.0;
    for (int i = threadIdx.x; i < nparts; i += 256) {
        neg += ws[3 * i + 0];
        pos += ws[3 * i + 1];
        cnt += ws[3 * i + 2];
    }
    block_reduce3(neg, pos, cnt);
    if (threadIdx.x == 0) {
        double r = (cnt == 0.0) ? (-neg) : (-(pos + neg) / cnt);
        out[0] = (float)r;
    }
}

extern "C" void kernel_launch(void* const* d_in, const int* in_sizes, int n_in,
                              void* d_out, int out_size, void* d_ws, size_t ws_size,
                              hipStream_t stream) {
    const float* outp = (const float*)d_in[0];
    const float* tgtp = (const float*)d_in[1];
    const int n  = in_sizes[0];
    const int n4 = n >> 2;            // float4 count
    const int tail_start = n4 << 2;

    double* ws = (double*)d_ws;
    int blocks = 2048;                 // 8 blocks/CU at 256 thr = full occupancy
    const int max_blocks = (int)(ws_size / (3 * sizeof(double)));
    if (blocks > max_blocks) blocks = max_blocks;
    if (blocks < 1) blocks = 1;

    ffl_partial<<<blocks, 256, 0, stream>>>(
        (const f32x4*)outp, (const f32x4*)tgtp, n4,
        outp, tgtp, tail_start, n, ws);
    ffl_final<<<1, 256, 0, stream>>>(ws, blocks, (float*)d_out);
}

// Round 8
// 71.559 us; speedup vs baseline: 2.4707x; 1.0167x over previous
//
#include <hip/hip_runtime.h>

// FastFocalLoss: scalar = -(pos_loss + neg_loss)/num_pos  (or -neg_loss if no pos)
//   neg_loss = sum log(1-o) * o^2 * (1-t)^4     over all elements
//   pos_loss = sum_{t==1} log(o) * (1-o)^2
//   num_pos  = count(t == 1.0)
// R7 post-mortem: all-nt = 72.75us (~6.0 TB/s effective, 95% of copy ceiling);
// mixed random caching was the old limiter. R8 probe: per-stream split —
// 'out' (201MB) cached => stays L3-resident across replays (256MB L3, nt
// 'target' never pollutes it); 'target' nt from HBM. Tests whether L3-hit
// return path ADDS to HBM read BW (aggregate > 6.3 TB/s possible) or the
// front end caps total at ~6 TB/s regardless of source.

typedef __attribute__((ext_vector_type(4))) float f32x4;

__device__ __forceinline__ double wave_reduce_add(double v) {
    #pragma unroll
    for (int off = 32; off > 0; off >>= 1) v += __shfl_down(v, off, 64);
    return v;
}

// Block-level reduce of three doubles (256 threads = 4 waves).
__device__ __forceinline__ void block_reduce3(double& neg, double& pos, double& cnt) {
    __shared__ double s_neg[4], s_pos[4], s_cnt[4];
    neg = wave_reduce_add(neg);
    pos = wave_reduce_add(pos);
    cnt = wave_reduce_add(cnt);
    const int lane = threadIdx.x & 63;
    const int wid  = threadIdx.x >> 6;
    if (lane == 0) { s_neg[wid] = neg; s_pos[wid] = pos; s_cnt[wid] = cnt; }
    __syncthreads();
    if (wid == 0) {
        neg = (lane < 4) ? s_neg[lane] : 0.0;
        pos = (lane < 4) ? s_pos[lane] : 0.0;
        cnt = (lane < 4) ? s_cnt[lane] : 0.0;
        #pragma unroll
        for (int off = 2; off > 0; off >>= 1) {
            neg += __shfl_down(neg, off, 64);
            pos += __shfl_down(pos, off, 64);
            cnt += __shfl_down(cnt, off, 64);
        }
    }
}

__device__ __forceinline__ void accum_elem(float o, float t,
                                           float& neg, float& pos, int& cnt) {
    float g  = 1.0f - t;
    float g2 = g * g;
    neg += __logf(1.0f - o) * (o * o) * (g2 * g2);
    if (t == 1.0f) {
        float io = 1.0f - o;
        pos += __logf(o) * io * io;
        cnt += 1;
    }
}

__global__ __launch_bounds__(256)
void ffl_partial(const f32x4* __restrict__ out4, const f32x4* __restrict__ tgt4,
                 int n4,
                 const float* __restrict__ out_s, const float* __restrict__ tgt_s,
                 int tail_start, int n,
                 double* __restrict__ ws) {
    float negf = 0.0f, posf = 0.0f;
    int cnt = 0;
    const int idx    = (int)blockIdx.x * 256 + (int)threadIdx.x;
    const int stride = (int)gridDim.x * 256;

    #pragma unroll 4
    for (int i = idx; i < n4; i += stride) {
        f32x4 o = out4[i];                               // cached: L3-resident
        f32x4 t = __builtin_nontemporal_load(&tgt4[i]);  // nt: stream from HBM
        accum_elem(o.x, t.x, negf, posf, cnt);
        accum_elem(o.y, t.y, negf, posf, cnt);
        accum_elem(o.z, t.z, negf, posf, cnt);
        accum_elem(o.w, t.w, negf, posf, cnt);
    }
    // scalar tail (n not divisible by 4)
    for (int j = tail_start + idx; j < n; j += stride) {
        float o = out_s[j];
        float t = __builtin_nontemporal_load(&tgt_s[j]);
        accum_elem(o, t, negf, posf, cnt);
    }

    double neg = (double)negf, pos = (double)posf, c = (double)cnt;
    block_reduce3(neg, pos, c);
    if (threadIdx.x == 0) {
        ws[3 * blockIdx.x + 0] = neg;
        ws[3 * blockIdx.x + 1] = pos;
        ws[3 * blockIdx.x + 2] = c;
    }
}

__global__ __launch_bounds__(256)
void ffl_final(const double* __restrict__ ws, int nparts, float* __restrict__ out) {
    double neg = 0.0, pos = 0.0, cnt = 0.0;
    for (int i = threadIdx.x; i < nparts; i += 256) {
        neg += ws[3 * i + 0];
        pos += ws[3 * i + 1];
        cnt += ws[3 * i + 2];
    }
    block_reduce3(neg, pos, cnt);
    if (threadIdx.x == 0) {
        double r = (cnt == 0.0) ? (-neg) : (-(pos + neg) / cnt);
        out[0] = (float)r;
    }
}

extern "C" void kernel_launch(void* const* d_in, const int* in_sizes, int n_in,
                              void* d_out, int out_size, void* d_ws, size_t ws_size,
                              hipStream_t stream) {
    const float* outp = (const float*)d_in[0];
    const float* tgtp = (const float*)d_in[1];
    const int n  = in_sizes[0];
    const int n4 = n >> 2;            // float4 count
    const int tail_start = n4 << 2;

    double* ws = (double*)d_ws;
    int blocks = 2048;                 // 8 blocks/CU at 256 thr = full occupancy
    const int max_blocks = (int)(ws_size / (3 * sizeof(double)));
    if (blocks > max_blocks) blocks = max_blocks;
    if (blocks < 1) blocks = 1;

    ffl_partial<<<blocks, 256, 0, stream>>>(
        (const f32x4*)outp, (const f32x4*)tgtp, n4,
        outp, tgtp, tail_start, n, ws);
    ffl_final<<<1, 256, 0, stream>>>(ws, blocks, (float*)d_out);
}